// Round 1
// baseline (1905.140 us; speedup 1.0000x reference)
//
#include <hip/hip_runtime.h>
#include <stdint.h>

#define B_    16
#define N_    4096
#define CPTS  64
#define S_    1024
#define K_    32

typedef __bf16 bf16x8 __attribute__((ext_vector_type(8)));
typedef float  f32x4  __attribute__((ext_vector_type(4)));

__device__ __forceinline__ float fmul_(float a, float b){ return __fmul_rn(a,b); }
__device__ __forceinline__ float fadd_(float a, float b){ return __fadd_rn(a,b); }
__device__ __forceinline__ float fsub_(float a, float b){ return __fsub_rn(a,b); }

__device__ __forceinline__ unsigned short f2bf(float f){
  unsigned u = __float_as_uint(f);
  unsigned r = (u + 0x7FFFu + ((u >> 16) & 1u)) >> 16;
  return (unsigned short)r;
}

__device__ __forceinline__ f32x4 mfma_16x16x32(bf16x8 a, bf16x8 b, f32x4 c){
  return __builtin_amdgcn_mfma_f32_16x16x32_bf16(a, b, c, 0, 0, 0);
}

__device__ __forceinline__ unsigned long long umin64(unsigned long long a, unsigned long long b){
  return b < a ? b : a;
}

// ---------------------------------------------------------------------------
// FPS: one block per batch. 1024 threads, 4 points/thread in registers.
// Emits new_xyz (output 0) directly.
// ---------------------------------------------------------------------------
__global__ __launch_bounds__(1024) void fps_kernel(const float* __restrict__ xyz,
                                                   float* __restrict__ out_newxyz)
{
  const int b   = blockIdx.x;
  const int tid = threadIdx.x;
  __shared__ float lx[N_], ly[N_], lz[N_];
  __shared__ unsigned long long wc[2][16];

  const float* xb = xyz + (size_t)b * (N_*3);
  float px[4], py[4], pz[4], dmin[4];
#pragma unroll
  for (int i = 0; i < 4; ++i) {
    int n = i*1024 + tid;
    float x = xb[n*3+0], y = xb[n*3+1], z = xb[n*3+2];
    lx[n]=x; ly[n]=y; lz[n]=z;
    px[i]=x; py[i]=y; pz[i]=z;
    dmin[i] = INFINITY;
  }
  __syncthreads();

  int far = 0;
  for (int step = 0; step < S_; ++step) {
    if (tid == 0) {
      float* o = out_newxyz + ((size_t)b*S_ + step)*3;
      o[0]=lx[far]; o[1]=ly[far]; o[2]=lz[far];
    }
    float cx = lx[far], cy = ly[far], cz = lz[far];
    float bval = -1.0f; unsigned bidx = 0;
#pragma unroll
    for (int i = 0; i < 4; ++i) {
      int n = i*1024 + tid;
      float dx = fsub_(px[i],cx), dy = fsub_(py[i],cy), dz = fsub_(pz[i],cz);
      float d  = fadd_(fadd_(fmul_(dx,dx),fmul_(dy,dy)),fmul_(dz,dz));
      float dm = fminf(dmin[i], d);
      dmin[i] = dm;
      bool gt = dm > bval;            // strict > keeps first occurrence (ascending n)
      bval = gt ? dm : bval;
      bidx = gt ? (unsigned)n : bidx;
    }
    // pack: value bits high (dmin>=0 so monotone), ~idx low (max => min idx on ties)
    unsigned long long kv = ((unsigned long long)__float_as_uint(bval) << 32) | (unsigned)(~bidx);
#pragma unroll
    for (int m = 1; m <= 32; m <<= 1) {
      unsigned long long o = __shfl_xor(kv, m, 64);
      kv = (o > kv) ? o : kv;
    }
    int par = step & 1;
    if ((tid & 63) == 0) wc[par][tid >> 6] = kv;
    __syncthreads();
    unsigned long long best = wc[par][0];
#pragma unroll
    for (int w = 1; w < 16; ++w) {
      unsigned long long o = wc[par][w];
      best = (o > best) ? o : best;
    }
    far = (int)(~(unsigned)best);
  }
}

// ---------------------------------------------------------------------------
// kNN: top-32 of 4096 per query, wave-per-query, exact with top_k tie-break.
// ---------------------------------------------------------------------------
#define KNN_REB(G) { \
  if (isw) { \
    if      (jj==0u) sk[(G)*8+0]=0xFFFFFFFFu; else if (jj==1u) sk[(G)*8+1]=0xFFFFFFFFu; \
    else if (jj==2u) sk[(G)*8+2]=0xFFFFFFFFu; else if (jj==3u) sk[(G)*8+3]=0xFFFFFFFFu; \
    else if (jj==4u) sk[(G)*8+4]=0xFFFFFFFFu; else if (jj==5u) sk[(G)*8+5]=0xFFFFFFFFu; \
    else if (jj==6u) sk[(G)*8+6]=0xFFFFFFFFu; else              sk[(G)*8+7]=0xFFFFFFFFu; } \
  { unsigned bk = sk[(G)*8+0]; unsigned bi = (unsigned)(((G)*8+0)*64 + lane); \
    _Pragma("unroll") \
    for (int j2 = 1; j2 < 8; ++j2) { \
      unsigned k2 = sk[(G)*8+j2]; unsigned i2 = (unsigned)(((G)*8+j2)*64 + lane); \
      bool lt = k2 < bk; bk = lt ? k2 : bk; bi = lt ? i2 : bi; } \
    gk[(G)] = bk; gi[(G)] = bi; } }

__global__ __launch_bounds__(256) void knn_kernel(const float* __restrict__ xyz,
                                                  const float* __restrict__ newxyz,
                                                  int* __restrict__ knn)
{
  __shared__ float4 lp[N_];  // x,y,z,dst2  (64 KB exactly)
  const int b     = blockIdx.x >> 6;
  const int chunk = blockIdx.x & 63;
  const float* xb = xyz + (size_t)b * (N_*3);
  for (int e = threadIdx.x; e < N_; e += 256) {
    float x = xb[e*3+0], y = xb[e*3+1], z = xb[e*3+2];
    float d2 = fadd_(fadd_(fmul_(x,x),fmul_(y,y)),fmul_(z,z));
    lp[e] = make_float4(x,y,z,d2);
  }
  __syncthreads();

  const int wave = threadIdx.x >> 6, lane = threadIdx.x & 63;
  for (int qi = 0; qi < 4; ++qi) {
    const int s  = chunk*16 + wave*4 + qi;
    const int fq = b*S_ + s;
    float qx = newxyz[fq*3+0], qy = newxyz[fq*3+1], qz = newxyz[fq*3+2];
    float s2 = fadd_(fadd_(fmul_(qx,qx),fmul_(qy,qy)),fmul_(qz,qz));

    unsigned sk[64];
#pragma unroll
    for (int j = 0; j < 64; ++j) {
      float4 p = lp[j*64 + lane];
      float dot = fadd_(fadd_(fmul_(qx,p.x),fmul_(qy,p.y)),fmul_(qz,p.z));
      float d   = fadd_(fsub_(s2, fmul_(2.0f,dot)), p.w);
      unsigned u = __float_as_uint(d);
      sk[j] = u ^ ((unsigned)((int)u >> 31) | 0x80000000u);  // sortable (handles tiny negatives)
    }
    unsigned gk[8], gi[8];
#pragma unroll
    for (int g = 0; g < 8; ++g) {
      unsigned bk = sk[g*8+0], bi = (unsigned)((g*8+0)*64 + lane);
#pragma unroll
      for (int j = 1; j < 8; ++j) {
        unsigned k2 = sk[g*8+j]; unsigned i2 = (unsigned)((g*8+j)*64 + lane);
        bool lt = k2 < bk; bk = lt ? k2 : bk; bi = lt ? i2 : bi;
      }
      gk[g]=bk; gi[g]=bi;
    }
    int* ko = knn + (size_t)fq * K_;
    for (int it = 0; it < K_; ++it) {
      unsigned long long c0 = ((unsigned long long)gk[0] << 32) | gi[0];
      unsigned long long c1 = ((unsigned long long)gk[1] << 32) | gi[1];
      unsigned long long c2 = ((unsigned long long)gk[2] << 32) | gi[2];
      unsigned long long c3 = ((unsigned long long)gk[3] << 32) | gi[3];
      unsigned long long c4 = ((unsigned long long)gk[4] << 32) | gi[4];
      unsigned long long c5 = ((unsigned long long)gk[5] << 32) | gi[5];
      unsigned long long c6 = ((unsigned long long)gk[6] << 32) | gi[6];
      unsigned long long c7 = ((unsigned long long)gk[7] << 32) | gi[7];
      c0 = umin64(c0,c1); c2 = umin64(c2,c3); c4 = umin64(c4,c5); c6 = umin64(c6,c7);
      c0 = umin64(c0,c2); c4 = umin64(c4,c6);
      unsigned long long cand = umin64(c0,c4);
#pragma unroll
      for (int m = 1; m <= 32; m <<= 1) {
        unsigned long long o = __shfl_xor(cand, m, 64);
        cand = (o < cand) ? o : cand;
      }
      unsigned widx = (unsigned)cand;
      if (lane == 0) ko[it] = (int)widx;
      unsigned wl = widx & 63u, wj = widx >> 6;
      unsigned g = wj >> 3, jj = wj & 7u;
      bool isw = (lane == (int)wl);
      switch (g) {
        case 0: KNN_REB(0); break;
        case 1: KNN_REB(1); break;
        case 2: KNN_REB(2); break;
        case 3: KNN_REB(3); break;
        case 4: KNN_REB(4); break;
        case 5: KNN_REB(5); break;
        case 6: KNN_REB(6); break;
        default: KNN_REB(7); break;
      }
    }
  }
}

// ---------------------------------------------------------------------------
// MLP chain: block = 4 queries = 128 rows. bf16 MFMA 16x16x32.
// STAGE 1/2/3: accumulate per-channel sum/sumsq of layer STAGE's pre-BN z.
// STAGE 4: full chain + BN3 + ReLU + max over K -> output 1.
// ---------------------------------------------------------------------------
template<int KS, int NT>
__device__ __forceinline__ void layer_mfma(const unsigned short* A, const unsigned short* W,
                                           int wstride, f32x4 (&acc)[2][NT], int wave, int lane)
{
  const int quad = lane >> 4, row0 = lane & 15;
  bf16x8 a[2][KS];
#pragma unroll
  for (int m2 = 0; m2 < 2; ++m2)
#pragma unroll
    for (int ks = 0; ks < KS; ++ks)
      a[m2][ks] = *(const bf16x8*)&A[((wave*2+m2)*16 + row0)*104 + ks*32 + quad*8];
#pragma unroll
  for (int m2 = 0; m2 < 2; ++m2)
#pragma unroll
    for (int n = 0; n < NT; ++n)
      acc[m2][n] = (f32x4){0.f,0.f,0.f,0.f};
#pragma unroll
  for (int n = 0; n < NT; ++n) {
#pragma unroll
    for (int ks = 0; ks < KS; ++ks) {
      bf16x8 bfrag = *(const bf16x8*)&W[(n*16 + row0)*wstride + ks*32 + quad*8];
      acc[0][n] = mfma_16x16x32(a[0][ks], bfrag, acc[0][n]);
      acc[1][n] = mfma_16x16x32(a[1][ks], bfrag, acc[1][n]);
    }
  }
}

template<int NT>
__device__ __forceinline__ void stats_ep(const f32x4 (&acc)[2][NT], float* sum, float* sq, int lane)
{
  const int part = blockIdx.x & 63;
  const int col0 = lane & 15;
#pragma unroll
  for (int n = 0; n < NT; ++n) {
    float s = 0.f, q = 0.f;
#pragma unroll
    for (int m2 = 0; m2 < 2; ++m2)
#pragma unroll
      for (int t = 0; t < 4; ++t) { float z = acc[m2][n][t]; s += z; q += z*z; }
    s += __shfl_xor(s, 16, 64); q += __shfl_xor(q, 16, 64);
    s += __shfl_xor(s, 32, 64); q += __shfl_xor(q, 32, 64);
    if (lane < 16) {
      atomicAdd(&sum[part*128 + n*16 + col0], s);
      atomicAdd(&sq [part*128 + n*16 + col0], q);
    }
  }
}

template<int NT>
__device__ __forceinline__ void bn_store(const f32x4 (&acc)[2][NT], unsigned short* A,
                                         const float* lmu, const float* lrsg, const float* lbeta,
                                         int off, int wave, int quad, int col0)
{
#pragma unroll
  for (int n = 0; n < NT; ++n) {
    int c = n*16 + col0;
    float mu = lmu[off+c], rg = lrsg[off+c], bt = lbeta[off+c];
#pragma unroll
    for (int m2 = 0; m2 < 2; ++m2)
#pragma unroll
      for (int t = 0; t < 4; ++t) {
        int row = (wave*2+m2)*16 + quad*4 + t;
        float v = fmaxf((acc[m2][n][t] - mu)*rg + bt, 0.0f);
        A[row*104 + c] = f2bf(v);
      }
  }
}

template<int STAGE>
__global__ __launch_bounds__(256) void mlp_kernel(
    const float* __restrict__ xyz, const float* __restrict__ pts,
    const float* __restrict__ W0, const float* __restrict__ g0, const float* __restrict__ be0,
    const float* __restrict__ W1, const float* __restrict__ g1, const float* __restrict__ be1,
    const float* __restrict__ W2, const float* __restrict__ g2, const float* __restrict__ be2,
    const float* __restrict__ newxyz, const int* __restrict__ knn,
    float* __restrict__ stats, float* __restrict__ out1)
{
  __shared__ unsigned short sA[128*104];   // activations, stride 104 (pad: banks + K pad to 96)
  __shared__ unsigned short wb[128*72];    // weights (W0 uses stride 104: 64*104 <= 128*72)
  __shared__ float lmu[256], lrsg[256], lbeta[256];

  const int tid  = threadIdx.x;
  const int wave = tid >> 6, lane = tid & 63;
  const int quad = lane >> 4, col0 = lane & 15;

  // ---- load BN stats of prior layers (tiny) ----
  {
    const int nl = STAGE - 1;
    const int   couts[3] = {64,64,128};
    const int   offs[3]  = {0,64,128};
    const float* gs[3]   = {g0,g1,g2};
    const float* bs[3]   = {be0,be1,be2};
    for (int l = 0; l < nl; ++l) {
      if (tid < couts[l]) {
        const float* su = stats + (size_t)(2*l)*8192;
        const float* sq = stats + (size_t)(2*l+1)*8192;
        float sm = 0.f, q = 0.f;
        for (int p = 0; p < 64; ++p) { sm += su[p*128+tid]; q += sq[p*128+tid]; }
        float mu  = sm * (1.0f/524288.0f);
        float var = q  * (1.0f/524288.0f) - mu*mu;
        float rs  = rsqrtf(var + 1e-5f);
        lmu [offs[l]+tid] = mu;
        lrsg[offs[l]+tid] = rs * gs[l][tid];
        lbeta[offs[l]+tid] = bs[l][tid];
      }
    }
  }

  // ---- gather grouped input into sA (bf16), cols 0..2 xyz-norm, 3..66 points, 67..95 zero ----
  {
    const int r = tid >> 1, half = tid & 1;
    const int ql = r >> 5, kk = r & 31;
    const int fq = blockIdx.x*4 + ql;
    const int b  = fq >> 10;
    const int p  = knn[(size_t)fq*K_ + kk];
    const float* prow = pts + ((size_t)(b<<12) + p) * CPTS;
    unsigned short* arow = &sA[r*104];
    const float4* p4 = (const float4*)prow;
    if (half == 0) {
      const float* xr = xyz + ((size_t)(b<<12) + p)*3;
      float qx = newxyz[fq*3+0], qy = newxyz[fq*3+1], qz = newxyz[fq*3+2];
      arow[0] = f2bf(fsub_(xr[0],qx));
      arow[1] = f2bf(fsub_(xr[1],qy));
      arow[2] = f2bf(fsub_(xr[2],qz));
#pragma unroll
      for (int i = 0; i < 8; ++i) {
        float4 v = p4[i];
        arow[3+i*4+0]=f2bf(v.x); arow[3+i*4+1]=f2bf(v.y);
        arow[3+i*4+2]=f2bf(v.z); arow[3+i*4+3]=f2bf(v.w);
      }
    } else {
#pragma unroll
      for (int i = 8; i < 16; ++i) {
        float4 v = p4[i];
        arow[3+i*4+0]=f2bf(v.x); arow[3+i*4+1]=f2bf(v.y);
        arow[3+i*4+2]=f2bf(v.z); arow[3+i*4+3]=f2bf(v.w);
      }
#pragma unroll
      for (int c = 67; c < 96; ++c) arow[c] = 0;
    }
  }

  // ---- W0 -> wb (stride 104, zero-padded K 67..95) ----
  {
    const int n = tid >> 2, k0 = (tid & 3) * 24;
#pragma unroll
    for (int j = 0; j < 24; ++j) {
      int k = k0 + j;
      wb[n*104 + k] = (k < 67) ? f2bf(W0[n*67 + k]) : (unsigned short)0;
    }
  }
  __syncthreads();

  // ---- layer 0: (128 x 96) @ (96 x 64) ----
  f32x4 acc0[2][4];
  layer_mfma<3,4>(sA, wb, 104, acc0, wave, lane);
  __syncthreads();
  if constexpr (STAGE == 1) { stats_ep<4>(acc0, stats + 0*8192, stats + 1*8192, lane); return; }

  bn_store<4>(acc0, sA, lmu, lrsg, lbeta, 0, wave, quad, col0);
  {
    const int n = tid >> 2, k0 = (tid & 3) * 16;
    const float4* w4 = (const float4*)(W1 + n*64 + k0);
#pragma unroll
    for (int i = 0; i < 4; ++i) {
      float4 v = w4[i];
      wb[n*72 + k0 + i*4 + 0]=f2bf(v.x); wb[n*72 + k0 + i*4 + 1]=f2bf(v.y);
      wb[n*72 + k0 + i*4 + 2]=f2bf(v.z); wb[n*72 + k0 + i*4 + 3]=f2bf(v.w);
    }
  }
  __syncthreads();

  // ---- layer 1: (128 x 64) @ (64 x 64) ----
  f32x4 acc1[2][4];
  layer_mfma<2,4>(sA, wb, 72, acc1, wave, lane);
  __syncthreads();
  if constexpr (STAGE == 2) { stats_ep<4>(acc1, stats + 2*8192, stats + 3*8192, lane); return; }

  bn_store<4>(acc1, sA, lmu, lrsg, lbeta, 64, wave, quad, col0);
  {
    const int n = tid >> 1, k0 = (tid & 1) * 32;
    const float4* w4 = (const float4*)(W2 + n*64 + k0);
#pragma unroll
    for (int i = 0; i < 8; ++i) {
      float4 v = w4[i];
      wb[n*72 + k0 + i*4 + 0]=f2bf(v.x); wb[n*72 + k0 + i*4 + 1]=f2bf(v.y);
      wb[n*72 + k0 + i*4 + 2]=f2bf(v.z); wb[n*72 + k0 + i*4 + 3]=f2bf(v.w);
    }
  }
  __syncthreads();

  // ---- layer 2: (128 x 64) @ (64 x 128) ----
  f32x4 acc2[2][8];
  layer_mfma<2,8>(sA, wb, 72, acc2, wave, lane);
  if constexpr (STAGE == 3) { stats_ep<8>(acc2, stats + 4*8192, stats + 5*8192, lane); return; }

  // ---- final: BN3 + ReLU + max over K (wave == query) ----
  {
    const int fq = blockIdx.x*4 + wave;
#pragma unroll
    for (int n = 0; n < 8; ++n) {
      int c = n*16 + col0;
      float mu = lmu[128+c], rg = lrsg[128+c], bt = lbeta[128+c];
      float mx = -INFINITY;
#pragma unroll
      for (int m2 = 0; m2 < 2; ++m2)
#pragma unroll
        for (int t = 0; t < 4; ++t) {
          float v = fmaxf((acc2[m2][n][t] - mu)*rg + bt, 0.0f);
          mx = fmaxf(mx, v);
        }
      mx = fmaxf(mx, __shfl_xor(mx, 16, 64));
      mx = fmaxf(mx, __shfl_xor(mx, 32, 64));
      if (lane < 16) out1[(size_t)fq*128 + c] = mx;
    }
  }
}

// ---------------------------------------------------------------------------
extern "C" void kernel_launch(void* const* d_in, const int* in_sizes, int n_in,
                              void* d_out, int out_size, void* d_ws, size_t ws_size,
                              hipStream_t stream)
{
  (void)in_sizes; (void)n_in; (void)out_size; (void)ws_size;
  const float* xyz  = (const float*)d_in[0];
  const float* pts  = (const float*)d_in[1];
  const float* W0   = (const float*)d_in[2];
  const float* g0   = (const float*)d_in[3];
  const float* be0  = (const float*)d_in[4];
  const float* W1   = (const float*)d_in[5];
  const float* g1   = (const float*)d_in[6];
  const float* be1  = (const float*)d_in[7];
  const float* W2   = (const float*)d_in[8];
  const float* g2   = (const float*)d_in[9];
  const float* be2  = (const float*)d_in[10];

  float* out  = (float*)d_out;                   // new_xyz: 16*1024*3
  float* out1 = out + (size_t)B_*S_*3;           // features: 16*1024*128
  int*   knn   = (int*)d_ws;                                     // 2 MB
  float* stats = (float*)((char*)d_ws + (size_t)B_*S_*K_*4);     // 6*8192 floats

  hipMemsetAsync(stats, 0, (size_t)6*8192*sizeof(float), stream);
  fps_kernel<<<16, 1024, 0, stream>>>(xyz, out);
  knn_kernel<<<1024, 256, 0, stream>>>(xyz, out, knn);
  mlp_kernel<1><<<4096, 256, 0, stream>>>(xyz, pts, W0,g0,be0, W1,g1,be1, W2,g2,be2, out, knn, stats, out1);
  mlp_kernel<2><<<4096, 256, 0, stream>>>(xyz, pts, W0,g0,be0, W1,g1,be1, W2,g2,be2, out, knn, stats, out1);
  mlp_kernel<3><<<4096, 256, 0, stream>>>(xyz, pts, W0,g0,be0, W1,g1,be1, W2,g2,be2, out, knn, stats, out1);
  mlp_kernel<4><<<4096, 256, 0, stream>>>(xyz, pts, W0,g0,be0, W1,g1,be1, W2,g2,be2, out, knn, stats, out1);
}

// Round 2
// 1517.596 us; speedup vs baseline: 1.2554x; 1.2554x over previous
//
#include <hip/hip_runtime.h>
#include <stdint.h>

#define B_    16
#define N_    4096
#define CPTS  64
#define S_    1024
#define K_    32

typedef __bf16 bf16x8 __attribute__((ext_vector_type(8)));
typedef float  f32x4  __attribute__((ext_vector_type(4)));
typedef unsigned short ushort8 __attribute__((ext_vector_type(8)));

__device__ __forceinline__ float fmul_(float a, float b){ return __fmul_rn(a,b); }
__device__ __forceinline__ float fadd_(float a, float b){ return __fadd_rn(a,b); }
__device__ __forceinline__ float fsub_(float a, float b){ return __fsub_rn(a,b); }

__device__ __forceinline__ unsigned short f2bf(float f){
  unsigned u = __float_as_uint(f);
  unsigned r = (u + 0x7FFFu + ((u >> 16) & 1u)) >> 16;
  return (unsigned short)r;
}

__device__ __forceinline__ f32x4 mfma_16x16x32(bf16x8 a, bf16x8 b, f32x4 c){
  return __builtin_amdgcn_mfma_f32_16x16x32_bf16(a, b, c, 0, 0, 0);
}

__device__ __forceinline__ unsigned long long umin64(unsigned long long a, unsigned long long b){
  return b < a ? b : a;
}
__device__ __forceinline__ unsigned long long umax64(unsigned long long a, unsigned long long b){
  return a < b ? b : a;
}

// ---------------------------------------------------------------------------
// FPS: one block per batch, 256 threads, 16 points/thread in registers.
// Per step: in-thread 4-level tree argmax (packed u64, ~idx tiebreak) ->
// 6-level wave shuffle -> 4 cross-wave entries via LDS, 1 barrier (parity).
// ---------------------------------------------------------------------------
__global__ __launch_bounds__(256) void fps_kernel(const float* __restrict__ xyz,
                                                  float* __restrict__ out_newxyz)
{
  const int b   = blockIdx.x;
  const int tid = threadIdx.x;
  const int wave = tid >> 6;
  __shared__ float lx[N_], ly[N_], lz[N_];
  __shared__ unsigned long long wc[2][4];

  const float* xb = xyz + (size_t)b * (N_*3);
  float px[16], py[16], pz[16], dmin[16];
#pragma unroll
  for (int i = 0; i < 16; ++i) {
    int n = i*256 + tid;
    float x = xb[n*3+0], y = xb[n*3+1], z = xb[n*3+2];
    lx[n]=x; ly[n]=y; lz[n]=z;
    px[i]=x; py[i]=y; pz[i]=z;
    dmin[i] = INFINITY;
  }
  __syncthreads();

  int far = 0;
  for (int step = 0; step < S_; ++step) {
    float cx = lx[far], cy = ly[far], cz = lz[far];
    if (tid == 0) {
      float* o = out_newxyz + ((size_t)b*S_ + step)*3;
      o[0]=cx; o[1]=cy; o[2]=cz;
    }
    unsigned long long c[16];
#pragma unroll
    for (int i = 0; i < 16; ++i) {
      float dx = fsub_(px[i],cx), dy = fsub_(py[i],cy), dz = fsub_(pz[i],cz);
      float d  = fadd_(fadd_(fmul_(dx,dx),fmul_(dy,dy)),fmul_(dz,dz));
      float dm = fminf(dmin[i], d);
      dmin[i] = dm;
      // pack: value bits high (dm>=0 so monotone), ~idx low (max => min idx on ties)
      c[i] = ((unsigned long long)__float_as_uint(dm) << 32) | (unsigned)(~(unsigned)(i*256 + tid));
    }
#pragma unroll
    for (int st = 8; st > 0; st >>= 1)
#pragma unroll
      for (int i = 0; i < 16; ++i) if (i < st) c[i] = umax64(c[i], c[i+st]);
    unsigned long long kv = c[0];
#pragma unroll
    for (int m = 1; m <= 32; m <<= 1) {
      unsigned long long o = __shfl_xor(kv, m, 64);
      kv = umax64(kv, o);
    }
    int par = step & 1;
    if ((tid & 63) == 0) wc[par][wave] = kv;
    __syncthreads();
    unsigned long long b0 = umax64(wc[par][0], wc[par][1]);
    unsigned long long b1 = umax64(wc[par][2], wc[par][3]);
    far = (int)(~(unsigned)umax64(b0, b1));
  }
}

// ---------------------------------------------------------------------------
// kNN: top-32 of 4096 per query, wave-per-query, exact with top_k tie-break.
// ---------------------------------------------------------------------------
#define KNN_REB(G) { \
  if (isw) { \
    if      (jj==0u) sk[(G)*8+0]=0xFFFFFFFFu; else if (jj==1u) sk[(G)*8+1]=0xFFFFFFFFu; \
    else if (jj==2u) sk[(G)*8+2]=0xFFFFFFFFu; else if (jj==3u) sk[(G)*8+3]=0xFFFFFFFFu; \
    else if (jj==4u) sk[(G)*8+4]=0xFFFFFFFFu; else if (jj==5u) sk[(G)*8+5]=0xFFFFFFFFu; \
    else if (jj==6u) sk[(G)*8+6]=0xFFFFFFFFu; else              sk[(G)*8+7]=0xFFFFFFFFu; } \
  { unsigned bk = sk[(G)*8+0]; unsigned bi = (unsigned)(((G)*8+0)*64 + lane); \
    _Pragma("unroll") \
    for (int j2 = 1; j2 < 8; ++j2) { \
      unsigned k2 = sk[(G)*8+j2]; unsigned i2 = (unsigned)(((G)*8+j2)*64 + lane); \
      bool lt = k2 < bk; bk = lt ? k2 : bk; bi = lt ? i2 : bi; } \
    gk[(G)] = bk; gi[(G)] = bi; } }

__global__ __launch_bounds__(256) void knn_kernel(const float* __restrict__ xyz,
                                                  const float* __restrict__ newxyz,
                                                  int* __restrict__ knn)
{
  __shared__ float4 lp[N_];  // x,y,z,dst2  (64 KB exactly)
  const int b     = blockIdx.x >> 6;
  const int chunk = blockIdx.x & 63;
  const float* xb = xyz + (size_t)b * (N_*3);
  for (int e = threadIdx.x; e < N_; e += 256) {
    float x = xb[e*3+0], y = xb[e*3+1], z = xb[e*3+2];
    float d2 = fadd_(fadd_(fmul_(x,x),fmul_(y,y)),fmul_(z,z));
    lp[e] = make_float4(x,y,z,d2);
  }
  __syncthreads();

  const int wave = threadIdx.x >> 6, lane = threadIdx.x & 63;
  for (int qi = 0; qi < 4; ++qi) {
    const int s  = chunk*16 + wave*4 + qi;
    const int fq = b*S_ + s;
    float qx = newxyz[fq*3+0], qy = newxyz[fq*3+1], qz = newxyz[fq*3+2];
    float s2 = fadd_(fadd_(fmul_(qx,qx),fmul_(qy,qy)),fmul_(qz,qz));

    unsigned sk[64];
#pragma unroll
    for (int j = 0; j < 64; ++j) {
      float4 p = lp[j*64 + lane];
      float dot = fadd_(fadd_(fmul_(qx,p.x),fmul_(qy,p.y)),fmul_(qz,p.z));
      float d   = fadd_(fsub_(s2, fmul_(2.0f,dot)), p.w);
      unsigned u = __float_as_uint(d);
      sk[j] = u ^ ((unsigned)((int)u >> 31) | 0x80000000u);  // sortable
    }
    unsigned gk[8], gi[8];
#pragma unroll
    for (int g = 0; g < 8; ++g) {
      unsigned bk = sk[g*8+0], bi = (unsigned)((g*8+0)*64 + lane);
#pragma unroll
      for (int j = 1; j < 8; ++j) {
        unsigned k2 = sk[g*8+j]; unsigned i2 = (unsigned)((g*8+j)*64 + lane);
        bool lt = k2 < bk; bk = lt ? k2 : bk; bi = lt ? i2 : bi;
      }
      gk[g]=bk; gi[g]=bi;
    }
    int* ko = knn + (size_t)fq * K_;
    for (int it = 0; it < K_; ++it) {
      unsigned long long c0 = ((unsigned long long)gk[0] << 32) | gi[0];
      unsigned long long c1 = ((unsigned long long)gk[1] << 32) | gi[1];
      unsigned long long c2 = ((unsigned long long)gk[2] << 32) | gi[2];
      unsigned long long c3 = ((unsigned long long)gk[3] << 32) | gi[3];
      unsigned long long c4 = ((unsigned long long)gk[4] << 32) | gi[4];
      unsigned long long c5 = ((unsigned long long)gk[5] << 32) | gi[5];
      unsigned long long c6 = ((unsigned long long)gk[6] << 32) | gi[6];
      unsigned long long c7 = ((unsigned long long)gk[7] << 32) | gi[7];
      c0 = umin64(c0,c1); c2 = umin64(c2,c3); c4 = umin64(c4,c5); c6 = umin64(c6,c7);
      c0 = umin64(c0,c2); c4 = umin64(c4,c6);
      unsigned long long cand = umin64(c0,c4);
#pragma unroll
      for (int m = 1; m <= 32; m <<= 1) {
        unsigned long long o = __shfl_xor(cand, m, 64);
        cand = (o < cand) ? o : cand;
      }
      unsigned widx = (unsigned)cand;
      if (lane == 0) ko[it] = (int)widx;
      unsigned wl = widx & 63u, wj = widx >> 6;
      unsigned g = wj >> 3, jj = wj & 7u;
      bool isw = (lane == (int)wl);
      switch (g) {
        case 0: KNN_REB(0); break;
        case 1: KNN_REB(1); break;
        case 2: KNN_REB(2); break;
        case 3: KNN_REB(3); break;
        case 4: KNN_REB(4); break;
        case 5: KNN_REB(5); break;
        case 6: KNN_REB(6); break;
        default: KNN_REB(7); break;
      }
    }
  }
}

// ---------------------------------------------------------------------------
// MLP chain: block = 4 queries = 128 rows. bf16 MFMA 16x16x32.
// A layout (K): cols 0..63 = points, 64..66 = xyz-norm, 67..95 = zero.
// W0 rows permuted identically, so the matmul is unchanged.
// ---------------------------------------------------------------------------
template<int KS, int NT>
__device__ __forceinline__ void layer_mfma(const unsigned short* A, const unsigned short* W,
                                           int wstride, f32x4 (&acc)[2][NT], int wave, int lane)
{
  const int quad = lane >> 4, row0 = lane & 15;
  bf16x8 a[2][KS];
#pragma unroll
  for (int m2 = 0; m2 < 2; ++m2)
#pragma unroll
    for (int ks = 0; ks < KS; ++ks)
      a[m2][ks] = *(const bf16x8*)&A[((wave*2+m2)*16 + row0)*104 + ks*32 + quad*8];
#pragma unroll
  for (int m2 = 0; m2 < 2; ++m2)
#pragma unroll
    for (int n = 0; n < NT; ++n)
      acc[m2][n] = (f32x4){0.f,0.f,0.f,0.f};
#pragma unroll
  for (int n = 0; n < NT; ++n) {
#pragma unroll
    for (int ks = 0; ks < KS; ++ks) {
      bf16x8 bfrag = *(const bf16x8*)&W[(n*16 + row0)*wstride + ks*32 + quad*8];
      acc[0][n] = mfma_16x16x32(a[0][ks], bfrag, acc[0][n]);
      acc[1][n] = mfma_16x16x32(a[1][ks], bfrag, acc[1][n]);
    }
  }
}

template<int NT>
__device__ __forceinline__ void stats_ep(const f32x4 (&acc)[2][NT], float* sum, float* sq, int lane)
{
  const int part = blockIdx.x & 63;
  const int col0 = lane & 15;
#pragma unroll
  for (int n = 0; n < NT; ++n) {
    float s = 0.f, q = 0.f;
#pragma unroll
    for (int m2 = 0; m2 < 2; ++m2)
#pragma unroll
      for (int t = 0; t < 4; ++t) { float z = acc[m2][n][t]; s += z; q += z*z; }
    s += __shfl_xor(s, 16, 64); q += __shfl_xor(q, 16, 64);
    s += __shfl_xor(s, 32, 64); q += __shfl_xor(q, 32, 64);
    if (lane < 16) {
      atomicAdd(&sum[part*128 + n*16 + col0], s);
      atomicAdd(&sq [part*128 + n*16 + col0], q);
    }
  }
}

template<int NT>
__device__ __forceinline__ void bn_store(const f32x4 (&acc)[2][NT], unsigned short* A,
                                         const float* lmu, const float* lrsg, const float* lbeta,
                                         int off, int wave, int quad, int col0)
{
#pragma unroll
  for (int n = 0; n < NT; ++n) {
    int c = n*16 + col0;
    float mu = lmu[off+c], rg = lrsg[off+c], bt = lbeta[off+c];
#pragma unroll
    for (int m2 = 0; m2 < 2; ++m2)
#pragma unroll
      for (int t = 0; t < 4; ++t) {
        int row = (wave*2+m2)*16 + quad*4 + t;
        float v = fmaxf((acc[m2][n][t] - mu)*rg + bt, 0.0f);
        A[row*104 + c] = f2bf(v);
      }
  }
}

template<int STAGE>
__global__ __launch_bounds__(256) void mlp_kernel(
    const float* __restrict__ xyz, const float* __restrict__ pts,
    const float* __restrict__ W0, const float* __restrict__ g0, const float* __restrict__ be0,
    const float* __restrict__ W1, const float* __restrict__ g1, const float* __restrict__ be1,
    const float* __restrict__ W2, const float* __restrict__ g2, const float* __restrict__ be2,
    const float* __restrict__ newxyz, const int* __restrict__ knn,
    float* __restrict__ stats, float* __restrict__ out1)
{
  __shared__ unsigned short sA[128*104];   // activations, stride 104 (13x16B -> conflict-free b128)
  __shared__ unsigned short wb[128*72];    // weights (W0 path uses stride 104: 64*104 <= 128*72)
  __shared__ float lmu[256], lrsg[256], lbeta[256];

  const int tid  = threadIdx.x;
  const int wave = tid >> 6, lane = tid & 63;
  const int quad = lane >> 4, col0 = lane & 15;

  // ---- load BN stats of prior layers (tiny) ----
  {
    const int nl = STAGE - 1;
    const int   couts[3] = {64,64,128};
    const int   offs[3]  = {0,64,128};
    const float* gs[3]   = {g0,g1,g2};
    const float* bs[3]   = {be0,be1,be2};
    for (int l = 0; l < nl; ++l) {
      if (tid < couts[l]) {
        const float* su = stats + (size_t)(2*l)*8192;
        const float* sq = stats + (size_t)(2*l+1)*8192;
        float sm = 0.f, q = 0.f;
        for (int p = 0; p < 64; ++p) { sm += su[p*128+tid]; q += sq[p*128+tid]; }
        float mu  = sm * (1.0f/524288.0f);
        float var = q  * (1.0f/524288.0f) - mu*mu;
        float rs  = rsqrtf(var + 1e-5f);
        lmu [offs[l]+tid] = mu;
        lrsg[offs[l]+tid] = rs * gs[l][tid];
        lbeta[offs[l]+tid] = bs[l][tid];
      }
    }
  }

  // ---- gather grouped input into sA (bf16), vectorized ushort8 stores ----
  {
    const int r = tid >> 1, half = tid & 1;
    const int ql = r >> 5, kk = r & 31;
    const int fq = blockIdx.x*4 + ql;
    const int b  = fq >> 10;
    const int p  = knn[(size_t)fq*K_ + kk];
    const float4* p4 = (const float4*)(pts + ((size_t)(b<<12) + p) * CPTS);
    ushort8* arow = (ushort8*)&sA[r*104];   // 208B rows -> 16B aligned
    if (half == 0) {
#pragma unroll
      for (int ch = 0; ch < 4; ++ch) {
        float4 a = p4[ch*2], bq = p4[ch*2+1];
        ushort8 v = { f2bf(a.x),f2bf(a.y),f2bf(a.z),f2bf(a.w),
                      f2bf(bq.x),f2bf(bq.y),f2bf(bq.z),f2bf(bq.w) };
        arow[ch] = v;
      }
    } else {
#pragma unroll
      for (int ch = 4; ch < 8; ++ch) {
        float4 a = p4[ch*2], bq = p4[ch*2+1];
        ushort8 v = { f2bf(a.x),f2bf(a.y),f2bf(a.z),f2bf(a.w),
                      f2bf(bq.x),f2bf(bq.y),f2bf(bq.z),f2bf(bq.w) };
        arow[ch] = v;
      }
      const float* xr = xyz + ((size_t)(b<<12) + p)*3;
      float qx = newxyz[fq*3+0], qy = newxyz[fq*3+1], qz = newxyz[fq*3+2];
      ushort8 vx = { f2bf(fsub_(xr[0],qx)), f2bf(fsub_(xr[1],qy)), f2bf(fsub_(xr[2],qz)),
                     0,0,0,0,0 };
      arow[8] = vx;
      ushort8 z = {0,0,0,0,0,0,0,0};
      arow[9] = z; arow[10] = z; arow[11] = z;
    }
  }

  // ---- W0 -> wb (stride 104, permuted cols, zero-padded) ----
  {
    const int n = tid >> 2, q = tid & 3;
    const float* wr = W0 + n*67;
#pragma unroll
    for (int ch = 0; ch < 3; ++ch) {
      int c0 = q*24 + ch*8;
      ushort8 v;
#pragma unroll
      for (int j = 0; j < 8; ++j) {
        int cc = c0 + j;
        float f = (cc < 64) ? wr[3+cc] : ((cc < 67) ? wr[cc-64] : 0.0f);
        v[j] = f2bf(f);
      }
      *(ushort8*)&wb[n*104 + c0] = v;
    }
  }
  __syncthreads();

  // ---- layer 0: (128 x 96) @ (96 x 64) ----
  f32x4 acc0[2][4];
  layer_mfma<3,4>(sA, wb, 104, acc0, wave, lane);
  __syncthreads();
  if constexpr (STAGE == 1) { stats_ep<4>(acc0, stats + 0*8192, stats + 1*8192, lane); return; }

  bn_store<4>(acc0, sA, lmu, lrsg, lbeta, 0, wave, quad, col0);
  {
    const int n = tid >> 2, k0 = (tid & 3) * 16;
    const float4* w4 = (const float4*)(W1 + n*64 + k0);
#pragma unroll
    for (int i = 0; i < 2; ++i) {
      float4 a = w4[i*2], bq = w4[i*2+1];
      ushort8 v = { f2bf(a.x),f2bf(a.y),f2bf(a.z),f2bf(a.w),
                    f2bf(bq.x),f2bf(bq.y),f2bf(bq.z),f2bf(bq.w) };
      ((ushort8*)&wb[n*72 + k0])[i] = v;
    }
  }
  __syncthreads();

  // ---- layer 1: (128 x 64) @ (64 x 64) ----
  f32x4 acc1[2][4];
  layer_mfma<2,4>(sA, wb, 72, acc1, wave, lane);
  __syncthreads();
  if constexpr (STAGE == 2) { stats_ep<4>(acc1, stats + 2*8192, stats + 3*8192, lane); return; }

  bn_store<4>(acc1, sA, lmu, lrsg, lbeta, 64, wave, quad, col0);
  {
    const int n = tid >> 1, k0 = (tid & 1) * 32;
    const float4* w4 = (const float4*)(W2 + n*64 + k0);
#pragma unroll
    for (int i = 0; i < 4; ++i) {
      float4 a = w4[i*2], bq = w4[i*2+1];
      ushort8 v = { f2bf(a.x),f2bf(a.y),f2bf(a.z),f2bf(a.w),
                    f2bf(bq.x),f2bf(bq.y),f2bf(bq.z),f2bf(bq.w) };
      ((ushort8*)&wb[n*72 + k0])[i] = v;
    }
  }
  __syncthreads();

  // ---- layer 2: (128 x 64) @ (64 x 128) ----
  f32x4 acc2[2][8];
  layer_mfma<2,8>(sA, wb, 72, acc2, wave, lane);
  if constexpr (STAGE == 3) { stats_ep<8>(acc2, stats + 4*8192, stats + 5*8192, lane); return; }

  // ---- final: BN3 + ReLU + max over K (wave == query) ----
  {
    const int fq = blockIdx.x*4 + wave;
#pragma unroll
    for (int n = 0; n < 8; ++n) {
      int c = n*16 + col0;
      float mu = lmu[128+c], rg = lrsg[128+c], bt = lbeta[128+c];
      float mx = -INFINITY;
#pragma unroll
      for (int m2 = 0; m2 < 2; ++m2)
#pragma unroll
        for (int t = 0; t < 4; ++t) {
          float v = fmaxf((acc2[m2][n][t] - mu)*rg + bt, 0.0f);
          mx = fmaxf(mx, v);
        }
      mx = fmaxf(mx, __shfl_xor(mx, 16, 64));
      mx = fmaxf(mx, __shfl_xor(mx, 32, 64));
      if (lane < 16) out1[(size_t)fq*128 + c] = mx;
    }
  }
}

// ---------------------------------------------------------------------------
extern "C" void kernel_launch(void* const* d_in, const int* in_sizes, int n_in,
                              void* d_out, int out_size, void* d_ws, size_t ws_size,
                              hipStream_t stream)
{
  (void)in_sizes; (void)n_in; (void)out_size; (void)ws_size;
  const float* xyz  = (const float*)d_in[0];
  const float* pts  = (const float*)d_in[1];
  const float* W0   = (const float*)d_in[2];
  const float* g0   = (const float*)d_in[3];
  const float* be0  = (const float*)d_in[4];
  const float* W1   = (const float*)d_in[5];
  const float* g1   = (const float*)d_in[6];
  const float* be1  = (const float*)d_in[7];
  const float* W2   = (const float*)d_in[8];
  const float* g2   = (const float*)d_in[9];
  const float* be2  = (const float*)d_in[10];

  float* out  = (float*)d_out;                   // new_xyz: 16*1024*3
  float* out1 = out + (size_t)B_*S_*3;           // features: 16*1024*128
  int*   knn   = (int*)d_ws;                                     // 2 MB
  float* stats = (float*)((char*)d_ws + (size_t)B_*S_*K_*4);     // 6*8192 floats

  hipMemsetAsync(stats, 0, (size_t)6*8192*sizeof(float), stream);
  fps_kernel<<<16, 256, 0, stream>>>(xyz, out);
  knn_kernel<<<1024, 256, 0, stream>>>(xyz, out, knn);
  mlp_kernel<1><<<4096, 256, 0, stream>>>(xyz, pts, W0,g0,be0, W1,g1,be1, W2,g2,be2, out, knn, stats, out1);
  mlp_kernel<2><<<4096, 256, 0, stream>>>(xyz, pts, W0,g0,be0, W1,g1,be1, W2,g2,be2, out, knn, stats, out1);
  mlp_kernel<3><<<4096, 256, 0, stream>>>(xyz, pts, W0,g0,be0, W1,g1,be1, W2,g2,be2, out, knn, stats, out1);
  mlp_kernel<4><<<4096, 256, 0, stream>>>(xyz, pts, W0,g0,be0, W1,g1,be1, W2,g2,be2, out, knn, stats, out1);
}

// Round 4
// 1479.370 us; speedup vs baseline: 1.2878x; 1.0258x over previous
//
#include <hip/hip_runtime.h>
#include <stdint.h>

#define B_    16
#define N_    4096
#define CPTS  64
#define S_    1024
#define K_    32

typedef __bf16 bf16x8 __attribute__((ext_vector_type(8)));
typedef float  f32x4  __attribute__((ext_vector_type(4)));
typedef unsigned short ushort8 __attribute__((ext_vector_type(8)));

__device__ __forceinline__ float fmul_(float a, float b){ return __fmul_rn(a,b); }
__device__ __forceinline__ float fadd_(float a, float b){ return __fadd_rn(a,b); }
__device__ __forceinline__ float fsub_(float a, float b){ return __fsub_rn(a,b); }

__device__ __forceinline__ unsigned short f2bf(float f){
  unsigned u = __float_as_uint(f);
  unsigned r = (u + 0x7FFFu + ((u >> 16) & 1u)) >> 16;
  return (unsigned short)r;
}

__device__ __forceinline__ f32x4 mfma_16x16x32(bf16x8 a, bf16x8 b, f32x4 c){
  return __builtin_amdgcn_mfma_f32_16x16x32_bf16(a, b, c, 0, 0, 0);
}

__device__ __forceinline__ unsigned long long umin64(unsigned long long a, unsigned long long b){
  return b < a ? b : a;
}
__device__ __forceinline__ unsigned long long umax64(unsigned long long a, unsigned long long b){
  return a < b ? b : a;
}

// ---------------------------------------------------------------------------
// FPS: one block per batch, 256 threads, 16 points/thread in registers.
// No global stores inside the step loop. fhist[s] = centroid index EMITTED at
// step s: fhist[0] = 0 (initial farthest), fhist[s+1] = winner of step s.
// ---------------------------------------------------------------------------
__global__ __launch_bounds__(256) void fps_kernel(const float* __restrict__ xyz,
                                                  float* __restrict__ out_newxyz)
{
  const int b   = blockIdx.x;
  const int tid = threadIdx.x;
  const int wave = tid >> 6;
  __shared__ float4 lp[N_];                 // 64 KB: x,y,z,0
  __shared__ unsigned long long wc[2][4];
  __shared__ int fhist[S_ + 1];             // fhist[s] = index emitted at step s

  const float* xb = xyz + (size_t)b * (N_*3);
  float px[16], py[16], pz[16], dmin[16];
#pragma unroll
  for (int i = 0; i < 16; ++i) {
    int n = i*256 + tid;
    float x = xb[n*3+0], y = xb[n*3+1], z = xb[n*3+2];
    lp[n] = make_float4(x,y,z,0.0f);
    px[i]=x; py[i]=y; pz[i]=z;
    dmin[i] = INFINITY;
  }
  if (tid == 0) fhist[0] = 0;
  __syncthreads();

  int far = 0;
  for (int step = 0; step < S_; ++step) {
    float4 cp = lp[far];                    // one ds_read_b128 (broadcast)
    float cx = cp.x, cy = cp.y, cz = cp.z;
    float bv = -1.0f; unsigned bidx = 0;
#pragma unroll
    for (int i = 0; i < 16; ++i) {
      float dx = fsub_(px[i],cx), dy = fsub_(py[i],cy), dz = fsub_(pz[i],cz);
      float d  = fadd_(fadd_(fmul_(dx,dx),fmul_(dy,dy)),fmul_(dz,dz));
      float dm = fminf(dmin[i], d);
      dmin[i] = dm;
      bool gt = dm > bv;                    // strict >: first (lowest i) wins ties
      bv   = gt ? dm : bv;
      bidx = gt ? (unsigned)(i*256 + tid) : bidx;
    }
    // bv >= 0 after i=0, so float bits are monotone; ~idx low => min idx on ties
    unsigned long long kv = ((unsigned long long)__float_as_uint(bv) << 32) | (unsigned)(~bidx);
#pragma unroll
    for (int m = 1; m <= 32; m <<= 1) {
      unsigned long long o = __shfl_xor(kv, m, 64);
      kv = umax64(kv, o);
    }
    int par = step & 1;
    if ((tid & 63) == 0) wc[par][wave] = kv;
    __syncthreads();
    unsigned long long b0 = umax64(wc[par][0], wc[par][1]);
    unsigned long long b1 = umax64(wc[par][2], wc[par][3]);
    far = (int)(~(unsigned)umax64(b0, b1));
    if (tid == 0) fhist[step + 1] = far;    // emitted at NEXT step (winner of this one)
  }
  __syncthreads();

  // epilogue: write all centroids coalesced (fhist[0..S_-1])
  float* ob = out_newxyz + (size_t)b*S_*3;
#pragma unroll
  for (int j = 0; j < 4; ++j) {
    int s = j*256 + tid;
    float4 p = lp[fhist[s]];
    ob[s*3+0] = p.x; ob[s*3+1] = p.y; ob[s*3+2] = p.z;
  }
}

// ---------------------------------------------------------------------------
// kNN: top-32 of 4096 per query, wave-per-query, exact with top_k tie-break.
// ---------------------------------------------------------------------------
#define KNN_REB(G) { \
  if (isw) { \
    if      (jj==0u) sk[(G)*8+0]=0xFFFFFFFFu; else if (jj==1u) sk[(G)*8+1]=0xFFFFFFFFu; \
    else if (jj==2u) sk[(G)*8+2]=0xFFFFFFFFu; else if (jj==3u) sk[(G)*8+3]=0xFFFFFFFFu; \
    else if (jj==4u) sk[(G)*8+4]=0xFFFFFFFFu; else if (jj==5u) sk[(G)*8+5]=0xFFFFFFFFu; \
    else if (jj==6u) sk[(G)*8+6]=0xFFFFFFFFu; else              sk[(G)*8+7]=0xFFFFFFFFu; } \
  { unsigned bk = sk[(G)*8+0]; unsigned bi = (unsigned)(((G)*8+0)*64 + lane); \
    _Pragma("unroll") \
    for (int j2 = 1; j2 < 8; ++j2) { \
      unsigned k2 = sk[(G)*8+j2]; unsigned i2 = (unsigned)(((G)*8+j2)*64 + lane); \
      bool lt = k2 < bk; bk = lt ? k2 : bk; bi = lt ? i2 : bi; } \
    gk[(G)] = bk; gi[(G)] = bi; } }

__global__ __launch_bounds__(256) void knn_kernel(const float* __restrict__ xyz,
                                                  const float* __restrict__ newxyz,
                                                  int* __restrict__ knn)
{
  __shared__ float4 lp[N_];  // x,y,z,dst2  (64 KB exactly)
  const int b     = blockIdx.x >> 6;
  const int chunk = blockIdx.x & 63;
  const float* xb = xyz + (size_t)b * (N_*3);
  for (int e = threadIdx.x; e < N_; e += 256) {
    float x = xb[e*3+0], y = xb[e*3+1], z = xb[e*3+2];
    float d2 = fadd_(fadd_(fmul_(x,x),fmul_(y,y)),fmul_(z,z));
    lp[e] = make_float4(x,y,z,d2);
  }
  __syncthreads();

  const int wave = threadIdx.x >> 6, lane = threadIdx.x & 63;
  for (int qi = 0; qi < 4; ++qi) {
    const int s  = chunk*16 + wave*4 + qi;
    const int fq = b*S_ + s;
    float qx = newxyz[fq*3+0], qy = newxyz[fq*3+1], qz = newxyz[fq*3+2];
    float s2 = fadd_(fadd_(fmul_(qx,qx),fmul_(qy,qy)),fmul_(qz,qz));

    unsigned sk[64];
#pragma unroll
    for (int j = 0; j < 64; ++j) {
      float4 p = lp[j*64 + lane];
      float dot = fadd_(fadd_(fmul_(qx,p.x),fmul_(qy,p.y)),fmul_(qz,p.z));
      float d   = fadd_(fsub_(s2, fmul_(2.0f,dot)), p.w);
      unsigned u = __float_as_uint(d);
      sk[j] = u ^ ((unsigned)((int)u >> 31) | 0x80000000u);  // sortable
    }
    unsigned gk[8], gi[8];
#pragma unroll
    for (int g = 0; g < 8; ++g) {
      unsigned bk = sk[g*8+0], bi = (unsigned)((g*8+0)*64 + lane);
#pragma unroll
      for (int j = 1; j < 8; ++j) {
        unsigned k2 = sk[g*8+j]; unsigned i2 = (unsigned)((g*8+j)*64 + lane);
        bool lt = k2 < bk; bk = lt ? k2 : bk; bi = lt ? i2 : bi;
      }
      gk[g]=bk; gi[g]=bi;
    }
    int* ko = knn + (size_t)fq * K_;
    for (int it = 0; it < K_; ++it) {
      unsigned long long c0 = ((unsigned long long)gk[0] << 32) | gi[0];
      unsigned long long c1 = ((unsigned long long)gk[1] << 32) | gi[1];
      unsigned long long c2 = ((unsigned long long)gk[2] << 32) | gi[2];
      unsigned long long c3 = ((unsigned long long)gk[3] << 32) | gi[3];
      unsigned long long c4 = ((unsigned long long)gk[4] << 32) | gi[4];
      unsigned long long c5 = ((unsigned long long)gk[5] << 32) | gi[5];
      unsigned long long c6 = ((unsigned long long)gk[6] << 32) | gi[6];
      unsigned long long c7 = ((unsigned long long)gk[7] << 32) | gi[7];
      c0 = umin64(c0,c1); c2 = umin64(c2,c3); c4 = umin64(c4,c5); c6 = umin64(c6,c7);
      c0 = umin64(c0,c2); c4 = umin64(c4,c6);
      unsigned long long cand = umin64(c0,c4);
#pragma unroll
      for (int m = 1; m <= 32; m <<= 1) {
        unsigned long long o = __shfl_xor(cand, m, 64);
        cand = (o < cand) ? o : cand;
      }
      unsigned widx = (unsigned)cand;
      if (lane == 0) ko[it] = (int)widx;
      unsigned wl = widx & 63u, wj = widx >> 6;
      unsigned g = wj >> 3, jj = wj & 7u;
      bool isw = (lane == (int)wl);
      switch (g) {
        case 0: KNN_REB(0); break;
        case 1: KNN_REB(1); break;
        case 2: KNN_REB(2); break;
        case 3: KNN_REB(3); break;
        case 4: KNN_REB(4); break;
        case 5: KNN_REB(5); break;
        case 6: KNN_REB(6); break;
        default: KNN_REB(7); break;
      }
    }
  }
}

// ---------------------------------------------------------------------------
// MLP chain: block = 4 queries = 128 rows. bf16 MFMA 16x16x32.
// A layout (K): cols 0..63 = points, 64..66 = xyz-norm, 67..95 = zero.
// W0 rows permuted identically, so the matmul is unchanged.
// ---------------------------------------------------------------------------
template<int KS, int NT>
__device__ __forceinline__ void layer_mfma(const unsigned short* A, const unsigned short* W,
                                           int wstride, f32x4 (&acc)[2][NT], int wave, int lane)
{
  const int quad = lane >> 4, row0 = lane & 15;
  bf16x8 a[2][KS];
#pragma unroll
  for (int m2 = 0; m2 < 2; ++m2)
#pragma unroll
    for (int ks = 0; ks < KS; ++ks)
      a[m2][ks] = *(const bf16x8*)&A[((wave*2+m2)*16 + row0)*104 + ks*32 + quad*8];
#pragma unroll
  for (int m2 = 0; m2 < 2; ++m2)
#pragma unroll
    for (int n = 0; n < NT; ++n)
      acc[m2][n] = (f32x4){0.f,0.f,0.f,0.f};
#pragma unroll
  for (int n = 0; n < NT; ++n) {
#pragma unroll
    for (int ks = 0; ks < KS; ++ks) {
      bf16x8 bfrag = *(const bf16x8*)&W[(n*16 + row0)*wstride + ks*32 + quad*8];
      acc[0][n] = mfma_16x16x32(a[0][ks], bfrag, acc[0][n]);
      acc[1][n] = mfma_16x16x32(a[1][ks], bfrag, acc[1][n]);
    }
  }
}

template<int NT>
__device__ __forceinline__ void stats_ep(const f32x4 (&acc)[2][NT], float* sum, float* sq, int lane)
{
  const int part = blockIdx.x & 63;
  const int col0 = lane & 15;
#pragma unroll
  for (int n = 0; n < NT; ++n) {
    float s = 0.f, q = 0.f;
#pragma unroll
    for (int m2 = 0; m2 < 2; ++m2)
#pragma unroll
      for (int t = 0; t < 4; ++t) { float z = acc[m2][n][t]; s += z; q += z*z; }
    s += __shfl_xor(s, 16, 64); q += __shfl_xor(q, 16, 64);
    s += __shfl_xor(s, 32, 64); q += __shfl_xor(q, 32, 64);
    if (lane < 16) {
      atomicAdd(&sum[part*128 + n*16 + col0], s);
      atomicAdd(&sq [part*128 + n*16 + col0], q);
    }
  }
}

template<int NT>
__device__ __forceinline__ void bn_store(const f32x4 (&acc)[2][NT], unsigned short* A,
                                         const float* lmu, const float* lrsg, const float* lbeta,
                                         int off, int wave, int quad, int col0)
{
#pragma unroll
  for (int n = 0; n < NT; ++n) {
    int c = n*16 + col0;
    float mu = lmu[off+c], rg = lrsg[off+c], bt = lbeta[off+c];
#pragma unroll
    for (int m2 = 0; m2 < 2; ++m2)
#pragma unroll
      for (int t = 0; t < 4; ++t) {
        int row = (wave*2+m2)*16 + quad*4 + t;
        float v = fmaxf((acc[m2][n][t] - mu)*rg + bt, 0.0f);
        A[row*104 + c] = f2bf(v);
      }
  }
}

template<int STAGE>
__global__ __launch_bounds__(256) void mlp_kernel(
    const float* __restrict__ xyz, const float* __restrict__ pts,
    const float* __restrict__ W0, const float* __restrict__ g0, const float* __restrict__ be0,
    const float* __restrict__ W1, const float* __restrict__ g1, const float* __restrict__ be1,
    const float* __restrict__ W2, const float* __restrict__ g2, const float* __restrict__ be2,
    const float* __restrict__ newxyz, const int* __restrict__ knn,
    float* __restrict__ stats, float* __restrict__ out1)
{
  __shared__ unsigned short sA[128*104];   // activations, stride 104 (13x16B -> conflict-free b128)
  __shared__ unsigned short wb[128*72];    // weights (W0 path uses stride 104: 64*104 <= 128*72)
  __shared__ float lmu[256], lrsg[256], lbeta[256];

  const int tid  = threadIdx.x;
  const int wave = tid >> 6, lane = tid & 63;
  const int quad = lane >> 4, col0 = lane & 15;

  // ---- load BN stats of prior layers (tiny) ----
  {
    const int nl = STAGE - 1;
    const int   couts[3] = {64,64,128};
    const int   offs[3]  = {0,64,128};
    const float* gs[3]   = {g0,g1,g2};
    const float* bs[3]   = {be0,be1,be2};
    for (int l = 0; l < nl; ++l) {
      if (tid < couts[l]) {
        const float* su = stats + (size_t)(2*l)*8192;
        const float* sq = stats + (size_t)(2*l+1)*8192;
        float sm = 0.f, q = 0.f;
        for (int p = 0; p < 64; ++p) { sm += su[p*128+tid]; q += sq[p*128+tid]; }
        float mu  = sm * (1.0f/524288.0f);
        float var = q  * (1.0f/524288.0f) - mu*mu;
        float rs  = rsqrtf(var + 1e-5f);
        lmu [offs[l]+tid] = mu;
        lrsg[offs[l]+tid] = rs * gs[l][tid];
        lbeta[offs[l]+tid] = bs[l][tid];
      }
    }
  }

  // ---- gather grouped input into sA (bf16), vectorized ushort8 stores ----
  {
    const int r = tid >> 1, half = tid & 1;
    const int ql = r >> 5, kk = r & 31;
    const int fq = blockIdx.x*4 + ql;
    const int b  = fq >> 10;
    const int p  = knn[(size_t)fq*K_ + kk];
    const float4* p4 = (const float4*)(pts + ((size_t)(b<<12) + p) * CPTS);
    ushort8* arow = (ushort8*)&sA[r*104];   // 208B rows -> 16B aligned
    if (half == 0) {
#pragma unroll
      for (int ch = 0; ch < 4; ++ch) {
        float4 a = p4[ch*2], bq = p4[ch*2+1];
        ushort8 v = { f2bf(a.x),f2bf(a.y),f2bf(a.z),f2bf(a.w),
                      f2bf(bq.x),f2bf(bq.y),f2bf(bq.z),f2bf(bq.w) };
        arow[ch] = v;
      }
    } else {
#pragma unroll
      for (int ch = 4; ch < 8; ++ch) {
        float4 a = p4[ch*2], bq = p4[ch*2+1];
        ushort8 v = { f2bf(a.x),f2bf(a.y),f2bf(a.z),f2bf(a.w),
                      f2bf(bq.x),f2bf(bq.y),f2bf(bq.z),f2bf(bq.w) };
        arow[ch] = v;
      }
      const float* xr = xyz + ((size_t)(b<<12) + p)*3;
      float qx = newxyz[fq*3+0], qy = newxyz[fq*3+1], qz = newxyz[fq*3+2];
      ushort8 vx = { f2bf(fsub_(xr[0],qx)), f2bf(fsub_(xr[1],qy)), f2bf(fsub_(xr[2],qz)),
                     0,0,0,0,0 };
      arow[8] = vx;
      ushort8 z = {0,0,0,0,0,0,0,0};
      arow[9] = z; arow[10] = z; arow[11] = z;
    }
  }

  // ---- W0 -> wb (stride 104, permuted cols, zero-padded) ----
  {
    const int n = tid >> 2, q = tid & 3;
    const float* wr = W0 + n*67;
#pragma unroll
    for (int ch = 0; ch < 3; ++ch) {
      int c0 = q*24 + ch*8;
      ushort8 v;
#pragma unroll
      for (int j = 0; j < 8; ++j) {
        int cc = c0 + j;
        float f = (cc < 64) ? wr[3+cc] : ((cc < 67) ? wr[cc-64] : 0.0f);
        v[j] = f2bf(f);
      }
      *(ushort8*)&wb[n*104 + c0] = v;
    }
  }
  __syncthreads();

  // ---- layer 0: (128 x 96) @ (96 x 64) ----
  f32x4 acc0[2][4];
  layer_mfma<3,4>(sA, wb, 104, acc0, wave, lane);
  __syncthreads();
  if constexpr (STAGE == 1) { stats_ep<4>(acc0, stats + 0*8192, stats + 1*8192, lane); return; }

  bn_store<4>(acc0, sA, lmu, lrsg, lbeta, 0, wave, quad, col0);
  {
    const int n = tid >> 2, k0 = (tid & 3) * 16;
    const float4* w4 = (const float4*)(W1 + n*64 + k0);
#pragma unroll
    for (int i = 0; i < 2; ++i) {
      float4 a = w4[i*2], bq = w4[i*2+1];
      ushort8 v = { f2bf(a.x),f2bf(a.y),f2bf(a.z),f2bf(a.w),
                    f2bf(bq.x),f2bf(bq.y),f2bf(bq.z),f2bf(bq.w) };
      ((ushort8*)&wb[n*72 + k0])[i] = v;
    }
  }
  __syncthreads();

  // ---- layer 1: (128 x 64) @ (64 x 64) ----
  f32x4 acc1[2][4];
  layer_mfma<2,4>(sA, wb, 72, acc1, wave, lane);
  __syncthreads();
  if constexpr (STAGE == 2) { stats_ep<4>(acc1, stats + 2*8192, stats + 3*8192, lane); return; }

  bn_store<4>(acc1, sA, lmu, lrsg, lbeta, 64, wave, quad, col0);
  {
    const int n = tid >> 1, k0 = (tid & 1) * 32;
    const float4* w4 = (const float4*)(W2 + n*64 + k0);
#pragma unroll
    for (int i = 0; i < 4; ++i) {
      float4 a = w4[i*2], bq = w4[i*2+1];
      ushort8 v = { f2bf(a.x),f2bf(a.y),f2bf(a.z),f2bf(a.w),
                    f2bf(bq.x),f2bf(bq.y),f2bf(bq.z),f2bf(bq.w) };
      ((ushort8*)&wb[n*72 + k0])[i] = v;
    }
  }
  __syncthreads();

  // ---- layer 2: (128 x 64) @ (64 x 128) ----
  f32x4 acc2[2][8];
  layer_mfma<2,8>(sA, wb, 72, acc2, wave, lane);
  if constexpr (STAGE == 3) { stats_ep<8>(acc2, stats + 4*8192, stats + 5*8192, lane); return; }

  // ---- final: BN3 + ReLU + max over K (wave == query) ----
  {
    const int fq = blockIdx.x*4 + wave;
#pragma unroll
    for (int n = 0; n < 8; ++n) {
      int c = n*16 + col0;
      float mu = lmu[128+c], rg = lrsg[128+c], bt = lbeta[128+c];
      float mx = -INFINITY;
#pragma unroll
      for (int m2 = 0; m2 < 2; ++m2)
#pragma unroll
        for (int t = 0; t < 4; ++t) {
          float v = fmaxf((acc2[m2][n][t] - mu)*rg + bt, 0.0f);
          mx = fmaxf(mx, v);
        }
      mx = fmaxf(mx, __shfl_xor(mx, 16, 64));
      mx = fmaxf(mx, __shfl_xor(mx, 32, 64));
      if (lane < 16) out1[(size_t)fq*128 + c] = mx;
    }
  }
}

// ---------------------------------------------------------------------------
extern "C" void kernel_launch(void* const* d_in, const int* in_sizes, int n_in,
                              void* d_out, int out_size, void* d_ws, size_t ws_size,
                              hipStream_t stream)
{
  (void)in_sizes; (void)n_in; (void)out_size; (void)ws_size;
  const float* xyz  = (const float*)d_in[0];
  const float* pts  = (const float*)d_in[1];
  const float* W0   = (const float*)d_in[2];
  const float* g0   = (const float*)d_in[3];
  const float* be0  = (const float*)d_in[4];
  const float* W1   = (const float*)d_in[5];
  const float* g1   = (const float*)d_in[6];
  const float* be1  = (const float*)d_in[7];
  const float* W2   = (const float*)d_in[8];
  const float* g2   = (const float*)d_in[9];
  const float* be2  = (const float*)d_in[10];

  float* out  = (float*)d_out;                   // new_xyz: 16*1024*3
  float* out1 = out + (size_t)B_*S_*3;           // features: 16*1024*128
  int*   knn   = (int*)d_ws;                                     // 2 MB
  float* stats = (float*)((char*)d_ws + (size_t)B_*S_*K_*4);     // 6*8192 floats

  hipMemsetAsync(stats, 0, (size_t)6*8192*sizeof(float), stream);
  fps_kernel<<<16, 256, 0, stream>>>(xyz, out);
  knn_kernel<<<1024, 256, 0, stream>>>(xyz, out, knn);
  mlp_kernel<1><<<4096, 256, 0, stream>>>(xyz, pts, W0,g0,be0, W1,g1,be1, W2,g2,be2, out, knn, stats, out1);
  mlp_kernel<2><<<4096, 256, 0, stream>>>(xyz, pts, W0,g0,be0, W1,g1,be1, W2,g2,be2, out, knn, stats, out1);
  mlp_kernel<3><<<4096, 256, 0, stream>>>(xyz, pts, W0,g0,be0, W1,g1,be1, W2,g2,be2, out, knn, stats, out1);
  mlp_kernel<4><<<4096, 256, 0, stream>>>(xyz, pts, W0,g0,be0, W1,g1,be1, W2,g2,be2, out, knn, stats, out1);
}

// Round 5
// 1351.376 us; speedup vs baseline: 1.4098x; 1.0947x over previous
//
#include <hip/hip_runtime.h>
#include <stdint.h>

#define B_    16
#define N_    4096
#define CPTS  64
#define S_    1024
#define K_    32

typedef __bf16 bf16x8 __attribute__((ext_vector_type(8)));
typedef float  f32x4  __attribute__((ext_vector_type(4)));
typedef unsigned short ushort8 __attribute__((ext_vector_type(8)));

__device__ __forceinline__ float fmul_(float a, float b){ return __fmul_rn(a,b); }
__device__ __forceinline__ float fadd_(float a, float b){ return __fadd_rn(a,b); }
__device__ __forceinline__ float fsub_(float a, float b){ return __fsub_rn(a,b); }

__device__ __forceinline__ unsigned short f2bf(float f){
  unsigned u = __float_as_uint(f);
  unsigned r = (u + 0x7FFFu + ((u >> 16) & 1u)) >> 16;
  return (unsigned short)r;
}

__device__ __forceinline__ f32x4 mfma_16x16x32(bf16x8 a, bf16x8 b, f32x4 c){
  return __builtin_amdgcn_mfma_f32_16x16x32_bf16(a, b, c, 0, 0, 0);
}

__device__ __forceinline__ unsigned long long umin64(unsigned long long a, unsigned long long b){
  return b < a ? b : a;
}
__device__ __forceinline__ unsigned long long umax64(unsigned long long a, unsigned long long b){
  return a < b ? b : a;
}

// DPP lane move: invalid source lanes keep old value (= identity for min/max).
template<int CTRL>
__device__ __forceinline__ unsigned dppmove(unsigned v){
  return (unsigned)__builtin_amdgcn_update_dpp((int)v, (int)v, CTRL, 0xF, 0xF, false);
}
// Wave64 max reduce in the VALU pipe; result broadcast via readlane(63).
__device__ __forceinline__ unsigned wave_umax_dpp(unsigned v){
  unsigned t;
  t = dppmove<0x111>(v); v = v > t ? v : t;   // row_shr:1
  t = dppmove<0x112>(v); v = v > t ? v : t;   // row_shr:2
  t = dppmove<0x114>(v); v = v > t ? v : t;   // row_shr:4
  t = dppmove<0x118>(v); v = v > t ? v : t;   // row_shr:8
  t = dppmove<0x142>(v); v = v > t ? v : t;   // row_bcast:15
  t = dppmove<0x143>(v); v = v > t ? v : t;   // row_bcast:31
  return (unsigned)__builtin_amdgcn_readlane((int)v, 63);
}

// ---------------------------------------------------------------------------
// FPS: one block per batch, 256 threads, 16 points/thread in registers.
// Per step: fused argmax scan -> two-phase DPP wave reduce (value max, then
// min-index among maxima; numpy first-index tie-break) -> 4-entry cross-wave
// LDS reduce with parity buffers (1 barrier/step). No global stores in-loop.
// fhist[0]=0, fhist[s+1]=winner of step s (emitted at the NEXT step).
// ---------------------------------------------------------------------------
__global__ __launch_bounds__(256) void fps_kernel(const float* __restrict__ xyz,
                                                  float* __restrict__ out_newxyz)
{
  const int b   = blockIdx.x;
  const int tid = threadIdx.x;
  const int wave = tid >> 6;
  __shared__ float4 lp[N_];                 // 64 KB: x,y,z,0
  __shared__ unsigned long long wc[2][4];
  __shared__ int fhist[S_ + 1];

  const float* xb = xyz + (size_t)b * (N_*3);
  float px[16], py[16], pz[16], dmin[16];
#pragma unroll
  for (int i = 0; i < 16; ++i) {
    int n = i*256 + tid;
    float x = xb[n*3+0], y = xb[n*3+1], z = xb[n*3+2];
    lp[n] = make_float4(x,y,z,0.0f);
    px[i]=x; py[i]=y; pz[i]=z;
    dmin[i] = INFINITY;
  }
  if (tid == 0) fhist[0] = 0;
  __syncthreads();

  int far = 0;
  for (int step = 0; step < S_; ++step) {
    float4 cp = lp[far];                    // one ds_read_b128 (broadcast)
    float cx = cp.x, cy = cp.y, cz = cp.z;
    float bv = -1.0f; unsigned bidx = 0;
#pragma unroll
    for (int i = 0; i < 16; ++i) {
      float dx = fsub_(px[i],cx), dy = fsub_(py[i],cy), dz = fsub_(pz[i],cz);
      float d  = fadd_(fadd_(fmul_(dx,dx),fmul_(dy,dy)),fmul_(dz,dz));
      float dm = fminf(dmin[i], d);
      dmin[i] = dm;
      bool gt = dm > bv;                    // strict >: first (lowest i) wins ties
      bv   = gt ? dm : bv;
      bidx = gt ? (unsigned)(i*256 + tid) : bidx;
    }
    // Phase A: wave max of distance bits (bv >= 0 so bits are order-monotone)
    unsigned bvb  = __float_as_uint(bv);
    unsigned wmax = wave_umax_dpp(bvb);
    // Phase B: min index among lanes holding the max (max of ~idx; 0 = identity)
    unsigned cand = (bvb == wmax) ? ~bidx : 0u;
    unsigned winv = wave_umax_dpp(cand);    // == ~(min matching index)
    unsigned long long kv = ((unsigned long long)wmax << 32) | winv;

    int par = step & 1;
    if ((tid & 63) == 0) wc[par][wave] = kv;
    __syncthreads();
    unsigned long long b0 = umax64(wc[par][0], wc[par][1]);
    unsigned long long b1 = umax64(wc[par][2], wc[par][3]);
    far = (int)(~(unsigned)umax64(b0, b1));
    if (tid == 0) fhist[step + 1] = far;
  }
  __syncthreads();

  // epilogue: write all centroids coalesced (fhist[0..S_-1])
  float* ob = out_newxyz + (size_t)b*S_*3;
#pragma unroll
  for (int j = 0; j < 4; ++j) {
    int s = j*256 + tid;
    float4 p = lp[fhist[s]];
    ob[s*3+0] = p.x; ob[s*3+1] = p.y; ob[s*3+2] = p.z;
  }
}

// ---------------------------------------------------------------------------
// kNN: top-32 of 4096 per query, wave-per-query, exact with top_k tie-break.
// ---------------------------------------------------------------------------
#define KNN_REB(G) { \
  if (isw) { \
    if      (jj==0u) sk[(G)*8+0]=0xFFFFFFFFu; else if (jj==1u) sk[(G)*8+1]=0xFFFFFFFFu; \
    else if (jj==2u) sk[(G)*8+2]=0xFFFFFFFFu; else if (jj==3u) sk[(G)*8+3]=0xFFFFFFFFu; \
    else if (jj==4u) sk[(G)*8+4]=0xFFFFFFFFu; else if (jj==5u) sk[(G)*8+5]=0xFFFFFFFFu; \
    else if (jj==6u) sk[(G)*8+6]=0xFFFFFFFFu; else              sk[(G)*8+7]=0xFFFFFFFFu; } \
  { unsigned bk = sk[(G)*8+0]; unsigned bi = (unsigned)(((G)*8+0)*64 + lane); \
    _Pragma("unroll") \
    for (int j2 = 1; j2 < 8; ++j2) { \
      unsigned k2 = sk[(G)*8+j2]; unsigned i2 = (unsigned)(((G)*8+j2)*64 + lane); \
      bool lt = k2 < bk; bk = lt ? k2 : bk; bi = lt ? i2 : bi; } \
    gk[(G)] = bk; gi[(G)] = bi; } }

__global__ __launch_bounds__(256) void knn_kernel(const float* __restrict__ xyz,
                                                  const float* __restrict__ newxyz,
                                                  int* __restrict__ knn)
{
  __shared__ float4 lp[N_];  // x,y,z,dst2  (64 KB exactly)
  const int b     = blockIdx.x >> 6;
  const int chunk = blockIdx.x & 63;
  const float* xb = xyz + (size_t)b * (N_*3);
  for (int e = threadIdx.x; e < N_; e += 256) {
    float x = xb[e*3+0], y = xb[e*3+1], z = xb[e*3+2];
    float d2 = fadd_(fadd_(fmul_(x,x),fmul_(y,y)),fmul_(z,z));
    lp[e] = make_float4(x,y,z,d2);
  }
  __syncthreads();

  const int wave = threadIdx.x >> 6, lane = threadIdx.x & 63;
  for (int qi = 0; qi < 4; ++qi) {
    const int s  = chunk*16 + wave*4 + qi;
    const int fq = b*S_ + s;
    float qx = newxyz[fq*3+0], qy = newxyz[fq*3+1], qz = newxyz[fq*3+2];
    float s2 = fadd_(fadd_(fmul_(qx,qx),fmul_(qy,qy)),fmul_(qz,qz));

    unsigned sk[64];
#pragma unroll
    for (int j = 0; j < 64; ++j) {
      float4 p = lp[j*64 + lane];
      float dot = fadd_(fadd_(fmul_(qx,p.x),fmul_(qy,p.y)),fmul_(qz,p.z));
      float d   = fadd_(fsub_(s2, fmul_(2.0f,dot)), p.w);
      unsigned u = __float_as_uint(d);
      sk[j] = u ^ ((unsigned)((int)u >> 31) | 0x80000000u);  // sortable
    }
    unsigned gk[8], gi[8];
#pragma unroll
    for (int g = 0; g < 8; ++g) {
      unsigned bk = sk[g*8+0], bi = (unsigned)((g*8+0)*64 + lane);
#pragma unroll
      for (int j = 1; j < 8; ++j) {
        unsigned k2 = sk[g*8+j]; unsigned i2 = (unsigned)((g*8+j)*64 + lane);
        bool lt = k2 < bk; bk = lt ? k2 : bk; bi = lt ? i2 : bi;
      }
      gk[g]=bk; gi[g]=bi;
    }
    int* ko = knn + (size_t)fq * K_;
    for (int it = 0; it < K_; ++it) {
      unsigned long long c0 = ((unsigned long long)gk[0] << 32) | gi[0];
      unsigned long long c1 = ((unsigned long long)gk[1] << 32) | gi[1];
      unsigned long long c2 = ((unsigned long long)gk[2] << 32) | gi[2];
      unsigned long long c3 = ((unsigned long long)gk[3] << 32) | gi[3];
      unsigned long long c4 = ((unsigned long long)gk[4] << 32) | gi[4];
      unsigned long long c5 = ((unsigned long long)gk[5] << 32) | gi[5];
      unsigned long long c6 = ((unsigned long long)gk[6] << 32) | gi[6];
      unsigned long long c7 = ((unsigned long long)gk[7] << 32) | gi[7];
      c0 = umin64(c0,c1); c2 = umin64(c2,c3); c4 = umin64(c4,c5); c6 = umin64(c6,c7);
      c0 = umin64(c0,c2); c4 = umin64(c4,c6);
      unsigned long long cand = umin64(c0,c4);
#pragma unroll
      for (int m = 1; m <= 32; m <<= 1) {
        unsigned long long o = __shfl_xor(cand, m, 64);
        cand = (o < cand) ? o : cand;
      }
      unsigned widx = (unsigned)cand;
      if (lane == 0) ko[it] = (int)widx;
      unsigned wl = widx & 63u, wj = widx >> 6;
      unsigned g = wj >> 3, jj = wj & 7u;
      bool isw = (lane == (int)wl);
      switch (g) {
        case 0: KNN_REB(0); break;
        case 1: KNN_REB(1); break;
        case 2: KNN_REB(2); break;
        case 3: KNN_REB(3); break;
        case 4: KNN_REB(4); break;
        case 5: KNN_REB(5); break;
        case 6: KNN_REB(6); break;
        default: KNN_REB(7); break;
      }
    }
  }
}

// ---------------------------------------------------------------------------
// MLP chain: block = 4 queries = 128 rows. bf16 MFMA 16x16x32.
// A layout (K): cols 0..63 = points, 64..66 = xyz-norm, 67..95 = zero.
// W0 rows permuted identically, so the matmul is unchanged.
// ---------------------------------------------------------------------------
template<int KS, int NT>
__device__ __forceinline__ void layer_mfma(const unsigned short* A, const unsigned short* W,
                                           int wstride, f32x4 (&acc)[2][NT], int wave, int lane)
{
  const int quad = lane >> 4, row0 = lane & 15;
  bf16x8 a[2][KS];
#pragma unroll
  for (int m2 = 0; m2 < 2; ++m2)
#pragma unroll
    for (int ks = 0; ks < KS; ++ks)
      a[m2][ks] = *(const bf16x8*)&A[((wave*2+m2)*16 + row0)*104 + ks*32 + quad*8];
#pragma unroll
  for (int m2 = 0; m2 < 2; ++m2)
#pragma unroll
    for (int n = 0; n < NT; ++n)
      acc[m2][n] = (f32x4){0.f,0.f,0.f,0.f};
#pragma unroll
  for (int n = 0; n < NT; ++n) {
#pragma unroll
    for (int ks = 0; ks < KS; ++ks) {
      bf16x8 bfrag = *(const bf16x8*)&W[(n*16 + row0)*wstride + ks*32 + quad*8];
      acc[0][n] = mfma_16x16x32(a[0][ks], bfrag, acc[0][n]);
      acc[1][n] = mfma_16x16x32(a[1][ks], bfrag, acc[1][n]);
    }
  }
}

template<int NT>
__device__ __forceinline__ void stats_ep(const f32x4 (&acc)[2][NT], float* sum, float* sq, int lane)
{
  const int part = blockIdx.x & 63;
  const int col0 = lane & 15;
#pragma unroll
  for (int n = 0; n < NT; ++n) {
    float s = 0.f, q = 0.f;
#pragma unroll
    for (int m2 = 0; m2 < 2; ++m2)
#pragma unroll
      for (int t = 0; t < 4; ++t) { float z = acc[m2][n][t]; s += z; q += z*z; }
    s += __shfl_xor(s, 16, 64); q += __shfl_xor(q, 16, 64);
    s += __shfl_xor(s, 32, 64); q += __shfl_xor(q, 32, 64);
    if (lane < 16) {
      atomicAdd(&sum[part*128 + n*16 + col0], s);
      atomicAdd(&sq [part*128 + n*16 + col0], q);
    }
  }
}

template<int NT>
__device__ __forceinline__ void bn_store(const f32x4 (&acc)[2][NT], unsigned short* A,
                                         const float* lmu, const float* lrsg, const float* lbeta,
                                         int off, int wave, int quad, int col0)
{
#pragma unroll
  for (int n = 0; n < NT; ++n) {
    int c = n*16 + col0;
    float mu = lmu[off+c], rg = lrsg[off+c], bt = lbeta[off+c];
#pragma unroll
    for (int m2 = 0; m2 < 2; ++m2)
#pragma unroll
      for (int t = 0; t < 4; ++t) {
        int row = (wave*2+m2)*16 + quad*4 + t;
        float v = fmaxf((acc[m2][n][t] - mu)*rg + bt, 0.0f);
        A[row*104 + c] = f2bf(v);
      }
  }
}

template<int STAGE>
__global__ __launch_bounds__(256) void mlp_kernel(
    const float* __restrict__ xyz, const float* __restrict__ pts,
    const float* __restrict__ W0, const float* __restrict__ g0, const float* __restrict__ be0,
    const float* __restrict__ W1, const float* __restrict__ g1, const float* __restrict__ be1,
    const float* __restrict__ W2, const float* __restrict__ g2, const float* __restrict__ be2,
    const float* __restrict__ newxyz, const int* __restrict__ knn,
    float* __restrict__ stats, float* __restrict__ out1)
{
  __shared__ unsigned short sA[128*104];   // activations, stride 104 (13x16B -> conflict-free b128)
  __shared__ unsigned short wb[128*72];    // weights (W0 path uses stride 104: 64*104 <= 128*72)
  __shared__ float lmu[256], lrsg[256], lbeta[256];

  const int tid  = threadIdx.x;
  const int wave = tid >> 6, lane = tid & 63;
  const int quad = lane >> 4, col0 = lane & 15;

  // ---- load BN stats of prior layers (tiny) ----
  {
    const int nl = STAGE - 1;
    const int   couts[3] = {64,64,128};
    const int   offs[3]  = {0,64,128};
    const float* gs[3]   = {g0,g1,g2};
    const float* bs[3]   = {be0,be1,be2};
    for (int l = 0; l < nl; ++l) {
      if (tid < couts[l]) {
        const float* su = stats + (size_t)(2*l)*8192;
        const float* sq = stats + (size_t)(2*l+1)*8192;
        float sm = 0.f, q = 0.f;
        for (int p = 0; p < 64; ++p) { sm += su[p*128+tid]; q += sq[p*128+tid]; }
        float mu  = sm * (1.0f/524288.0f);
        float var = q  * (1.0f/524288.0f) - mu*mu;
        float rs  = rsqrtf(var + 1e-5f);
        lmu [offs[l]+tid] = mu;
        lrsg[offs[l]+tid] = rs * gs[l][tid];
        lbeta[offs[l]+tid] = bs[l][tid];
      }
    }
  }

  // ---- gather grouped input into sA (bf16), vectorized ushort8 stores ----
  {
    const int r = tid >> 1, half = tid & 1;
    const int ql = r >> 5, kk = r & 31;
    const int fq = blockIdx.x*4 + ql;
    const int b  = fq >> 10;
    const int p  = knn[(size_t)fq*K_ + kk];
    const float4* p4 = (const float4*)(pts + ((size_t)(b<<12) + p) * CPTS);
    ushort8* arow = (ushort8*)&sA[r*104];   // 208B rows -> 16B aligned
    if (half == 0) {
#pragma unroll
      for (int ch = 0; ch < 4; ++ch) {
        float4 a = p4[ch*2], bq = p4[ch*2+1];
        ushort8 v = { f2bf(a.x),f2bf(a.y),f2bf(a.z),f2bf(a.w),
                      f2bf(bq.x),f2bf(bq.y),f2bf(bq.z),f2bf(bq.w) };
        arow[ch] = v;
      }
    } else {
#pragma unroll
      for (int ch = 4; ch < 8; ++ch) {
        float4 a = p4[ch*2], bq = p4[ch*2+1];
        ushort8 v = { f2bf(a.x),f2bf(a.y),f2bf(a.z),f2bf(a.w),
                      f2bf(bq.x),f2bf(bq.y),f2bf(bq.z),f2bf(bq.w) };
        arow[ch] = v;
      }
      const float* xr = xyz + ((size_t)(b<<12) + p)*3;
      float qx = newxyz[fq*3+0], qy = newxyz[fq*3+1], qz = newxyz[fq*3+2];
      ushort8 vx = { f2bf(fsub_(xr[0],qx)), f2bf(fsub_(xr[1],qy)), f2bf(fsub_(xr[2],qz)),
                     0,0,0,0,0 };
      arow[8] = vx;
      ushort8 z = {0,0,0,0,0,0,0,0};
      arow[9] = z; arow[10] = z; arow[11] = z;
    }
  }

  // ---- W0 -> wb (stride 104, permuted cols, zero-padded) ----
  {
    const int n = tid >> 2, q = tid & 3;
    const float* wr = W0 + n*67;
#pragma unroll
    for (int ch = 0; ch < 3; ++ch) {
      int c0 = q*24 + ch*8;
      ushort8 v;
#pragma unroll
      for (int j = 0; j < 8; ++j) {
        int cc = c0 + j;
        float f = (cc < 64) ? wr[3+cc] : ((cc < 67) ? wr[cc-64] : 0.0f);
        v[j] = f2bf(f);
      }
      *(ushort8*)&wb[n*104 + c0] = v;
    }
  }
  __syncthreads();

  // ---- layer 0: (128 x 96) @ (96 x 64) ----
  f32x4 acc0[2][4];
  layer_mfma<3,4>(sA, wb, 104, acc0, wave, lane);
  __syncthreads();
  if constexpr (STAGE == 1) { stats_ep<4>(acc0, stats + 0*8192, stats + 1*8192, lane); return; }

  bn_store<4>(acc0, sA, lmu, lrsg, lbeta, 0, wave, quad, col0);
  {
    const int n = tid >> 2, k0 = (tid & 3) * 16;
    const float4* w4 = (const float4*)(W1 + n*64 + k0);
#pragma unroll
    for (int i = 0; i < 2; ++i) {
      float4 a = w4[i*2], bq = w4[i*2+1];
      ushort8 v = { f2bf(a.x),f2bf(a.y),f2bf(a.z),f2bf(a.w),
                    f2bf(bq.x),f2bf(bq.y),f2bf(bq.z),f2bf(bq.w) };
      ((ushort8*)&wb[n*72 + k0])[i] = v;
    }
  }
  __syncthreads();

  // ---- layer 1: (128 x 64) @ (64 x 64) ----
  f32x4 acc1[2][4];
  layer_mfma<2,4>(sA, wb, 72, acc1, wave, lane);
  __syncthreads();
  if constexpr (STAGE == 2) { stats_ep<4>(acc1, stats + 2*8192, stats + 3*8192, lane); return; }

  bn_store<4>(acc1, sA, lmu, lrsg, lbeta, 64, wave, quad, col0);
  {
    const int n = tid >> 1, k0 = (tid & 1) * 32;
    const float4* w4 = (const float4*)(W2 + n*64 + k0);
#pragma unroll
    for (int i = 0; i < 4; ++i) {
      float4 a = w4[i*2], bq = w4[i*2+1];
      ushort8 v = { f2bf(a.x),f2bf(a.y),f2bf(a.z),f2bf(a.w),
                    f2bf(bq.x),f2bf(bq.y),f2bf(bq.z),f2bf(bq.w) };
      ((ushort8*)&wb[n*72 + k0])[i] = v;
    }
  }
  __syncthreads();

  // ---- layer 2: (128 x 64) @ (64 x 128) ----
  f32x4 acc2[2][8];
  layer_mfma<2,8>(sA, wb, 72, acc2, wave, lane);
  if constexpr (STAGE == 3) { stats_ep<8>(acc2, stats + 4*8192, stats + 5*8192, lane); return; }

  // ---- final: BN3 + ReLU + max over K (wave == query) ----
  {
    const int fq = blockIdx.x*4 + wave;
#pragma unroll
    for (int n = 0; n < 8; ++n) {
      int c = n*16 + col0;
      float mu = lmu[128+c], rg = lrsg[128+c], bt = lbeta[128+c];
      float mx = -INFINITY;
#pragma unroll
      for (int m2 = 0; m2 < 2; ++m2)
#pragma unroll
        for (int t = 0; t < 4; ++t) {
          float v = fmaxf((acc2[m2][n][t] - mu)*rg + bt, 0.0f);
          mx = fmaxf(mx, v);
        }
      mx = fmaxf(mx, __shfl_xor(mx, 16, 64));
      mx = fmaxf(mx, __shfl_xor(mx, 32, 64));
      if (lane < 16) out1[(size_t)fq*128 + c] = mx;
    }
  }
}

// ---------------------------------------------------------------------------
extern "C" void kernel_launch(void* const* d_in, const int* in_sizes, int n_in,
                              void* d_out, int out_size, void* d_ws, size_t ws_size,
                              hipStream_t stream)
{
  (void)in_sizes; (void)n_in; (void)out_size; (void)ws_size;
  const float* xyz  = (const float*)d_in[0];
  const float* pts  = (const float*)d_in[1];
  const float* W0   = (const float*)d_in[2];
  const float* g0   = (const float*)d_in[3];
  const float* be0  = (const float*)d_in[4];
  const float* W1   = (const float*)d_in[5];
  const float* g1   = (const float*)d_in[6];
  const float* be1  = (const float*)d_in[7];
  const float* W2   = (const float*)d_in[8];
  const float* g2   = (const float*)d_in[9];
  const float* be2  = (const float*)d_in[10];

  float* out  = (float*)d_out;                   // new_xyz: 16*1024*3
  float* out1 = out + (size_t)B_*S_*3;           // features: 16*1024*128
  int*   knn   = (int*)d_ws;                                     // 2 MB
  float* stats = (float*)((char*)d_ws + (size_t)B_*S_*K_*4);     // 6*8192 floats

  hipMemsetAsync(stats, 0, (size_t)6*8192*sizeof(float), stream);
  fps_kernel<<<16, 256, 0, stream>>>(xyz, out);
  knn_kernel<<<1024, 256, 0, stream>>>(xyz, out, knn);
  mlp_kernel<1><<<4096, 256, 0, stream>>>(xyz, pts, W0,g0,be0, W1,g1,be1, W2,g2,be2, out, knn, stats, out1);
  mlp_kernel<2><<<4096, 256, 0, stream>>>(xyz, pts, W0,g0,be0, W1,g1,be1, W2,g2,be2, out, knn, stats, out1);
  mlp_kernel<3><<<4096, 256, 0, stream>>>(xyz, pts, W0,g0,be0, W1,g1,be1, W2,g2,be2, out, knn, stats, out1);
  mlp_kernel<4><<<4096, 256, 0, stream>>>(xyz, pts, W0,g0,be0, W1,g1,be1, W2,g2,be2, out, knn, stats, out1);
}